// Round 18
// baseline (149.307 us; speedup 1.0000x reference)
//
#include <hip/hip_runtime.h>
#include <hip/hip_bf16.h>

#define NROWS 8192

typedef __bf16 bf16x8 __attribute__((ext_vector_type(8)));
typedef float f32x4 __attribute__((ext_vector_type(4)));
typedef unsigned short ushort_t;
typedef unsigned int uint_t;

__device__ __forceinline__ ushort_t f2bf(float f) {
  uint_t u = __builtin_bit_cast(uint_t, f);
  u += 0x7fffu + ((u >> 16) & 1u);   // round-to-nearest-even
  return (ushort_t)(u >> 16);
}
__device__ __forceinline__ float bf2f(ushort_t h) {
  uint_t u = ((uint_t)h) << 16;
  return __builtin_bit_cast(float, u);
}
// async global->LDS DMA; LDS dest = uniform base + lane*size
__device__ __forceinline__ void load_lds16(const ushort_t* g, ushort_t* l) {
  __builtin_amdgcn_global_load_lds(
      (const __attribute__((address_space(1))) unsigned int*)g,
      (__attribute__((address_space(3))) unsigned int*)l, 16, 0, 0);
}
__device__ __forceinline__ void load_lds4(const float* g, float* l) {
  __builtin_amdgcn_global_load_lds(
      (const __attribute__((address_space(1))) unsigned int*)g,
      (__attribute__((address_space(3))) unsigned int*)l, 4, 0, 0);
}

// ---------------------------------------------------------------------------
// prep_w: pack Wcat=[W1|W2] (fp32) into fragment-major bf16 Wf.
// ---------------------------------------------------------------------------
template<int DIN, int F>
__global__ __launch_bounds__(256) void prep_w_kernel(
    const float* __restrict__ W1, const float* __restrict__ W2,
    ushort_t* __restrict__ Wf)
{
  constexpr int NCT = (2 * F) / 16;
  int idx = blockIdx.x * 256 + threadIdx.x;   // grid sized exactly
  int e = idx & 7, lane = (idx >> 3) & 63;
  int ct = (idx >> 9) % NCT, kk = (idx >> 9) / NCT;
  int g = lane >> 4, q = lane & 15;
  int k = 32 * kk + 8 * g + e, c = 16 * ct + q;
  float v = (c < F) ? W1[(size_t)k * F + c] : W2[(size_t)k * F + (c - F)];
  Wf[idx] = f2bf(v);
}

// ---------------------------------------------------------------------------
// lin (R18): MFMA GEMM for [gl|h] = x @ [W1|W2] + b. RED=true (layer 1):
// x produced inline by reducing the 16 partial slabs (fused reduce_div).
// ---------------------------------------------------------------------------
template<int DIN, int F, bool RED>
__global__ __launch_bounds__(256) void lin_kernel(
    const float* __restrict__ x, const ushort_t* __restrict__ Wf,
    const float* __restrict__ b1, const float* __restrict__ b2,
    ushort_t* __restrict__ glf, float* __restrict__ sq, ushort_t* __restrict__ hf)
{
  constexpr int Fp   = F + 16;
  constexpr int NT   = Fp / 16;
  constexpr int KK   = F / 32;       // packer fragments (gl)
  constexpr int KKD  = DIN / 32;     // GEMM K-fragments
  constexpr int NCT  = (2 * F) / 16; // output col-tiles (gl|h)
  constexpr int NCTW = NCT / 4;      // col-tiles per wave
  __shared__ float    xs[16][DIN];
  __shared__ float    hs[16][F];
  __shared__ ushort_t gls[16][F];
  __shared__ float    sqs[16];
  __shared__ float    degs[16];
  const int t  = threadIdx.x;
  const int m  = blockIdx.x;
  const int r0 = m * 16;
  const int w = t >> 6, lane = t & 63, g = lane >> 4, q = lane & 15;

  if (RED) {
    // fused reduce_div over 16 slabs: deg first, then reduced elems into xs
    constexpr size_t STR = (size_t)NROWS * 144;
    if (t < 16) {
      float d = 0.f;
#pragma unroll
      for (int js = 0; js < 16; ++js)
        d += x[js * STR + (size_t)(r0 + t) * 144 + 128];
      degs[t] = d;
    }
    __syncthreads();
    for (int i = t; i < 16 * DIN; i += 256) {
      int r = i / DIN, c = i % DIN;
      float s = 0.f;
#pragma unroll
      for (int js = 0; js < 16; ++js)
        s += x[js * STR + (size_t)(r0 + r) * 144 + c];
      xs[r][c] = fmaxf(s, 0.f) / degs[r];
    }
  } else {
    for (int i = t; i < 16 * DIN; i += 256)
      xs[i / DIN][i % DIN] = x[(size_t)(r0 + i / DIN) * DIN + (i % DIN)];
  }
  if (t < 16) sqs[t] = 0.f;
  __syncthreads();

  // A-frags: lane(g,q) elem e = bf16(xs[q][32kk+8g+e])
  bf16x8 aF[KKD];
#pragma unroll
  for (int kk = 0; kk < KKD; ++kk) {
    const float* src = &xs[q][32 * kk + 8 * g];
    __align__(16) ushort_t tmp[8];
#pragma unroll
    for (int e = 0; e < 8; ++e) tmp[e] = f2bf(src[e]);
    aF[kk] = *(const bf16x8*)tmp;
  }
  // acc init = bias broadcast
  f32x4 acc[NCTW];
#pragma unroll
  for (int tl = 0; tl < NCTW; ++tl) {
    int c = 16 * (NCTW * w + tl) + q;
    float bv = (c < F) ? b1[c] : b2[c - F];
    acc[tl] = (f32x4){bv, bv, bv, bv};
  }
#pragma unroll
  for (int kk = 0; kk < KKD; ++kk)
#pragma unroll
    for (int tl = 0; tl < NCTW; ++tl) {
      bf16x8 bW = *(const bf16x8*)(Wf +
          ((size_t)(kk * NCT) + (NCTW * w + tl)) * 512 + lane * 8);
      acc[tl] = __builtin_amdgcn_mfma_f32_16x16x32_bf16(aF[kk], bW, acc[tl], 0, 0, 0);
    }
  // epilogue: D[row=4g+r][col=16ct+q] -> gls (relu+bf16, +sq) or hs
#pragma unroll
  for (int tl = 0; tl < NCTW; ++tl)
#pragma unroll
    for (int r = 0; r < 4; ++r) {
      int row = 4 * g + r, c = 16 * (NCTW * w + tl) + q;
      float v = acc[tl][r];
      if (c < F) {
        float gv = fmaxf(v, 0.f);
        ushort_t gb = f2bf(gv);
        gls[row][c] = gb;
        float gf = bf2f(gb);
        atomicAdd(&sqs[row], gf * gf);
      } else {
        hs[row][c - F] = v;
      }
    }
  __syncthreads();
  if (t < 16) sq[r0 + t] = sqs[t];

  // ---- glf writer (unchanged)
  {
    constexpr int CH = KK * 64;
    if (t < CH) {
      int kk = t >> 6, li = t & 63;
      int row = li & 15, c0 = 32 * kk + 8 * (li >> 4);
      uint4 v = *(const uint4*)&gls[row][c0];
      *(uint4*)(glf + ((size_t)(m * KK + kk) * 64 + li) * 8) = v;
    }
  }
  // ---- hf writer (unchanged)
  {
    const int jc  = m >> 2;
    const int P   = (m >> 1) & 1;
    const int glo = (m & 1) * 2;
    for (int idx = t; idx < NT * 32; idx += 256) {
      int t2 = idx >> 5, li = idx & 31;
      int gg = li >> 4, qq = li & 15;
      int feat = 16 * t2 + qq;
      ushort_t tmp[8];
#pragma unroll
      for (int e = 0; e < 8; ++e) {
        if (feat < F)        tmp[e] = f2bf(hs[8 * gg + e][feat]);
        else if (feat == F)  tmp[e] = (ushort_t)0x3F80;  // bf16(1.0)
        else                 tmp[e] = 0;
      }
      int ln = (glo + gg) * 16 + qq;
      uint4* dst = (uint4*)(hf + ((size_t)((jc * 2 + P) * NT + t2) * 64 + ln) * 8);
      *dst = *(const uint4*)tmp;
    }
  }
}

// ---------------------------------------------------------------------------
// fused (R18 = R17 + JS=16): discriminating test of the residency lever.
// R12's JS=16 null ran at 50KB LDS (2/CU if usable LDS ~144KB); this kernel
// is 25KB -> up to 5/CU. Grid (64,16) = 1024 blocks; bijective remap
// n -> (bx=n>>4, by=n&15): XCD k (n%8==k) serves j-chunks {k, k+8} only.
// ---------------------------------------------------------------------------
template<int F>
__global__ __launch_bounds__(256) void fused_kernel(
    const ushort_t* __restrict__ glf, const float* __restrict__ sq,
    const ushort_t* __restrict__ hf,
    const float* __restrict__ temp_p, const float* __restrict__ theta_p,
    float* __restrict__ partial)
{
  constexpr int Fp   = F + 16;
  constexpr int NT   = Fp / 16;
  constexpr int KK   = F / 32;
  constexpr int JS   = 16;
  constexpr int JCH  = NROWS / JS;   // 512 j-rows per block
  constexpr int NIT  = JCH / 32;     // 16 iterations
  constexpr int NCHB = 2 * KK;
  constexpr int NHF  = NT - 1;
  constexpr int NCH  = NCHB + NHF;
  constexpr float EPS = 1.1920929e-07f;
  constexpr float LOG2E = 1.4426950408889634f;
  __shared__ __align__(16) ushort_t stage[NCH * 512 + 128];
  __shared__ __align__(16) ushort_t adjlds[128 * 32];

  const int w = threadIdx.x >> 6, lane = threadIdx.x & 63;
  const int g = lane >> 4, q = lane & 15;
  const int n  = blockIdx.x + (int)gridDim.x * blockIdx.y;
  const int bx = n >> 4, by = n & 15;
  const int irow  = bx * 128 + 32 * w;
  const int jbase = by * JCH;
  const float c1 = 1.0f + *temp_p;
  const float c0 = 5.0f + *theta_p;
  const float k1 = c1 * LOG2E;
  const float k0 = -c0 * LOG2E;

  bf16x8 aF[2][KK];
#pragma unroll
  for (int s = 0; s < 2; ++s)
#pragma unroll
    for (int kk = 0; kk < KK; ++kk)
      aF[s][kk] = *(const bf16x8*)(glf +
          ((size_t)(((irow >> 4) + s) * KK + kk) * 64 + lane) * 8);
  float sqi[2][4];
#pragma unroll
  for (int s = 0; s < 2; ++s)
#pragma unroll
    for (int r = 0; r < 4; ++r) sqi[s][r] = sq[irow + 16 * s + 4 * g + r] + EPS;

  bf16x8 onesF;
  {
    __align__(16) ushort_t tmp[8];
    ushort_t v = (q == 0) ? (ushort_t)0x3F80 : (ushort_t)0;
#pragma unroll
    for (int e = 0; e < 8; ++e) tmp[e] = v;
    onesF = *(const bf16x8*)tmp;
  }

  ushort_t* wp[8];
#pragma unroll
  for (int tt = 0; tt < 2; ++tt)
#pragma unroll
    for (int r = 0; r < 4; ++r) {
      int row = 32 * w + 4 * g + r;
      int colb = 32 * tt + 2 * q;
      wp[tt * 4 + r] = (ushort_t*)((char*)adjlds
                        + row * 64 + (colb ^ (((row >> 2) & 3) << 4)));
    }
  const ushort_t* rp;
  {
    int row = 32 * w + q;
    rp = (const ushort_t*)((char*)adjlds
          + row * 64 + ((16 * g) ^ (((row >> 2) & 3) << 4)));
  }
  const float* sql = (const float*)(stage + NCH * 512) + q;

  f32x4 acc[2][NT];
#pragma unroll
  for (int s = 0; s < 2; ++s)
#pragma unroll
    for (int i = 0; i < NT; ++i) acc[s][i] = (f32x4){0.f, 0.f, 0.f, 0.f};

#pragma unroll 1
  for (int k = 0; k < NIT; ++k) {
    const int j0 = jbase + k * 32;
    __syncthreads();
    {
      const ushort_t* glB = glf + (size_t)(j0 >> 4) * KK * 512;
      const ushort_t* glH = hf  + (size_t)(j0 >> 5) * NT * 512;
#pragma unroll
      for (int ch = w; ch < NCH; ch += 4) {
        const ushort_t* src = (ch < NCHB) ? (glB + (size_t)ch * 512)
                                          : (glH + (size_t)(ch - NCHB) * 512);
        load_lds16(src + lane * 8, stage + ch * 512);
      }
      if (w == 3 && lane < 32)
        load_lds4(sq + j0 + lane, (float*)(stage + NCH * 512) + lane);
    }
    __syncthreads();

    f32x4 sA[2][2];
    float sqj[2];
#pragma unroll
    for (int tt = 0; tt < 2; ++tt) {
      sqj[tt] = sql[16 * tt];
      f32x4 c0a = (f32x4){0.f, 0.f, 0.f, 0.f};
      f32x4 c1a = (f32x4){0.f, 0.f, 0.f, 0.f};
#pragma unroll
      for (int kk = 0; kk < KK; ++kk) {
        bf16x8 b = *(const bf16x8*)(stage + (tt * KK + kk) * 512 + lane * 8);
        c0a = __builtin_amdgcn_mfma_f32_16x16x32_bf16(aF[0][kk], b, c0a, 0, 0, 0);
        c1a = __builtin_amdgcn_mfma_f32_16x16x32_bf16(aF[1][kk], b, c1a, 0, 0, 0);
      }
      sA[0][tt] = c0a;
      sA[1][tt] = c1a;
    }
#pragma unroll
    for (int s = 0; s < 2; ++s)
#pragma unroll
      for (int tt = 0; tt < 2; ++tt)
#pragma unroll
        for (int r = 0; r < 4; ++r) {
          float t1 = sqi[s][r] + sqj[tt];
          float d  = fmaxf(fmaf(-2.f, sA[s][tt][r], t1), EPS);
          float e  = __builtin_amdgcn_exp2f(
                       fmaf(k1, __builtin_amdgcn_sqrtf(d), k0));
          float adjv = __builtin_amdgcn_rcpf(1.f + e);
          uint_t u = __builtin_bit_cast(uint_t, adjv) + 0x8000u;
          *(wp[tt * 4 + r] + s * 512) = (ushort_t)(u >> 16);
        }
    asm volatile("s_waitcnt lgkmcnt(0)" ::: "memory");
    {
      bf16x8 aP0 = *(const bf16x8*)(rp);
      bf16x8 aP1 = *(const bf16x8*)(rp + 512);
#pragma unroll
      for (int t2 = 0; t2 < NT; ++t2) {
        bf16x8 hF = (t2 == NT - 1)
            ? onesF
            : *(const bf16x8*)(stage + (NCHB + t2) * 512 + lane * 8);
        acc[0][t2] = __builtin_amdgcn_mfma_f32_16x16x32_bf16(aP0, hF, acc[0][t2], 0, 0, 0);
        acc[1][t2] = __builtin_amdgcn_mfma_f32_16x16x32_bf16(aP1, hF, acc[1][t2], 0, 0, 0);
      }
    }
  }

  float* op = partial + ((size_t)by * NROWS + irow) * Fp;
#pragma unroll
  for (int s = 0; s < 2; ++s)
#pragma unroll
    for (int t2 = 0; t2 < NT; ++t2)
#pragma unroll
      for (int r = 0; r < 4; ++r)
        op[(size_t)(16 * s + 4 * g + r) * Fp + 16 * t2 + q] = acc[s][t2][r];
}

// out = softmax(sum_js(partial)/deg) rowwise; 4 rows/block (wave per row)
__global__ __launch_bounds__(256) void reduce_softmax_kernel(
    const float* __restrict__ partial, float* __restrict__ out)
{
  int t = threadIdx.x;
  int r = blockIdx.x * 4 + (t >> 6), c = t & 63;
  size_t base = (size_t)r * 80;
  size_t stride = (size_t)NROWS * 80;
  float v = 0.f, d = 0.f;
#pragma unroll
  for (int js = 0; js < 16; ++js) {
    v += partial[js * stride + base + c];
    d += partial[js * stride + base + 64];
  }
  v /= d;
  float m = v;
  for (int o = 32; o > 0; o >>= 1) m = fmaxf(m, __shfl_xor(m, o, 64));
  float e = __expf(v - m);
  float s = e;
  for (int o = 32; o > 0; o >>= 1) s += __shfl_xor(s, o, 64);
  out[(size_t)r * 64 + c] = e / s;
}

extern "C" void kernel_launch(void* const* d_in, const int* in_sizes, int n_in,
                              void* d_out, int out_size, void* d_ws, size_t ws_size,
                              hipStream_t stream) {
  const float* feat  = (const float*)d_in[0];
  const float* Wgl0  = (const float*)d_in[6];
  const float* bgl0  = (const float*)d_in[7];
  const float* Wgnn0 = (const float*)d_in[8];
  const float* bgnn0 = (const float*)d_in[9];
  const float* Wgl1  = (const float*)d_in[10];
  const float* bgl1  = (const float*)d_in[11];
  const float* Wgnn1 = (const float*)d_in[12];
  const float* bgnn1 = (const float*)d_in[13];
  const float* temp  = (const float*)d_in[14];
  const float* theta = (const float*)d_in[15];
  float* out = (float*)d_out;

  char* ws = (char*)d_ws;
  size_t off = 0;
  auto alloc = [&](size_t bytes) {
    char* p = ws + off;
    off = (off + bytes + 255) & ~(size_t)255;
    return p;
  };
  float*    par0 = (float*)alloc(16ull * NROWS * 144 * 4);  // 75.5 MB
  float*    par1 = par0;  // aliased: par0 fully consumed by lin1 first
  ushort_t* glf0 = (ushort_t*)alloc((8192ull / 16) * 4 * 64 * 8 * 2);
  ushort_t* glf1 = (ushort_t*)alloc((8192ull / 16) * 2 * 64 * 8 * 2);
  ushort_t* hf0  = (ushort_t*)alloc((8192ull / 64) * 2 * 9 * 64 * 8 * 2);
  ushort_t* hf1  = (ushort_t*)alloc((8192ull / 64) * 2 * 5 * 64 * 8 * 2);
  float*    sq0  = (float*)alloc(8192ull * 4);
  float*    sq1  = (float*)alloc(8192ull * 4);
  ushort_t* Wf0  = (ushort_t*)alloc(8ull * 16 * 512 * 2);   // 128 KB
  ushort_t* Wf1  = (ushort_t*)alloc(4ull * 8 * 512 * 2);    // 32 KB

  prep_w_kernel<256, 128><<<256, 256, 0, stream>>>(Wgl0, Wgnn0, Wf0);
  prep_w_kernel<128, 64><<<64, 256, 0, stream>>>(Wgl1, Wgnn1, Wf1);

  lin_kernel<256, 128, false><<<512, 256, 0, stream>>>(feat, Wf0, bgl0, bgnn0, glf0, sq0, hf0);
  fused_kernel<128><<<dim3(64, 16), 256, 0, stream>>>(glf0, sq0, hf0, temp, theta, par0);

  // lin1 fuses reduce_div: reads the 16 partial slabs directly
  lin_kernel<128, 64, true><<<512, 256, 0, stream>>>(par0, Wf1, bgl1, bgnn1, glf1, sq1, hf1);
  fused_kernel<64><<<dim3(64, 16), 256, 0, stream>>>(glf1, sq1, hf1, temp, theta, par1);
  reduce_softmax_kernel<<<2048, 256, 0, stream>>>(par1, out);
}

// Round 19
// 146.730 us; speedup vs baseline: 1.0176x; 1.0176x over previous
//
#include <hip/hip_runtime.h>
#include <hip/hip_bf16.h>

#define NROWS 8192

typedef __bf16 bf16x8 __attribute__((ext_vector_type(8)));
typedef float f32x4 __attribute__((ext_vector_type(4)));
typedef float f32x16 __attribute__((ext_vector_type(16)));
typedef unsigned int u32x2 __attribute__((ext_vector_type(2)));
typedef unsigned int u32x4 __attribute__((ext_vector_type(4)));
typedef unsigned short ushort_t;
typedef unsigned int uint_t;

__device__ __forceinline__ ushort_t f2bf(float f) {
  uint_t u = __builtin_bit_cast(uint_t, f);
  u += 0x7fffu + ((u >> 16) & 1u);   // round-to-nearest-even
  return (ushort_t)(u >> 16);
}
__device__ __forceinline__ float bf2f(ushort_t h) {
  uint_t u = ((uint_t)h) << 16;
  return __builtin_bit_cast(float, u);
}
// pack two f32 -> dword of 2 bf16 (lo = first arg)
__device__ __forceinline__ uint_t cvtpk(float lo, float hi) {
  uint_t r;
  asm("v_cvt_pk_bf16_f32 %0, %1, %2" : "=v"(r) : "v"(lo), "v"(hi));
  return r;
}
// async global->LDS DMA; LDS dest = uniform base + lane*size
__device__ __forceinline__ void load_lds16(const ushort_t* g, ushort_t* l) {
  __builtin_amdgcn_global_load_lds(
      (const __attribute__((address_space(1))) unsigned int*)g,
      (__attribute__((address_space(3))) unsigned int*)l, 16, 0, 0);
}
__device__ __forceinline__ void load_lds4(const float* g, float* l) {
  __builtin_amdgcn_global_load_lds(
      (const __attribute__((address_space(1))) unsigned int*)g,
      (__attribute__((address_space(3))) unsigned int*)l, 4, 0, 0);
}

// ---------------------------------------------------------------------------
// prep_w: pack Wcat=[W1|W2] (fp32) into fragment-major bf16 Wf (16x16 frags).
// ---------------------------------------------------------------------------
template<int DIN, int F>
__global__ __launch_bounds__(256) void prep_w_kernel(
    const float* __restrict__ W1, const float* __restrict__ W2,
    ushort_t* __restrict__ Wf)
{
  constexpr int NCT = (2 * F) / 16;
  int idx = blockIdx.x * 256 + threadIdx.x;   // grid sized exactly
  int e = idx & 7, lane = (idx >> 3) & 63;
  int ct = (idx >> 9) % NCT, kk = (idx >> 9) / NCT;
  int g = lane >> 4, q = lane & 15;
  int k = 32 * kk + 8 * g + e, c = 16 * ct + q;
  float v = (c < F) ? W1[(size_t)k * F + c] : W2[(size_t)k * F + (c - F)];
  Wf[idx] = f2bf(v);
}

// ---------------------------------------------------------------------------
// lin (R19): MFMA GEMM for [gl|h] = x @ [W1|W2] + b (16x16 frags, unchanged
// core). RED=true: x produced inline from the 8 partial slabs (stride 160).
// NEW writers emit 32x32-fragment-major outputs:
//   glf32[jt32][kk16][lane][8]: lane l holds gl[32jt32+(l&31)][16kk16+8(l>>5)+e]
//   hf32 [jw16][ft]  [lane][8]: lane l holds h[16jw16+8(l>>5)+e][32ft+(l&31)]
//   sq[r] = sum(bf16(gl[r])^2)
// ---------------------------------------------------------------------------
template<int DIN, int F, bool RED>
__global__ __launch_bounds__(256) void lin_kernel(
    const float* __restrict__ x, const ushort_t* __restrict__ Wf,
    const float* __restrict__ b1, const float* __restrict__ b2,
    ushort_t* __restrict__ glf32, float* __restrict__ sq, ushort_t* __restrict__ hf32)
{
  constexpr int KKD  = DIN / 32;     // GEMM K-fragments
  constexpr int NCT  = (2 * F) / 16; // output col-tiles (gl|h)
  constexpr int NCTW = NCT / 4;      // col-tiles per wave
  constexpr int FT   = F / 32;       // hf32 real f-tiles
  __shared__ float    xs[16][DIN];
  __shared__ float    hs[16][F];
  __shared__ ushort_t gls[16][F];
  __shared__ float    sqs[16];
  __shared__ float    degs[16];
  const int t  = threadIdx.x;
  const int m  = blockIdx.x;
  const int r0 = m * 16;
  const int w = t >> 6, lane = t & 63, g = lane >> 4, q = lane & 15;

  if (RED) {
    constexpr size_t STR = (size_t)NROWS * 160;
    if (t < 16) {
      float d = 0.f;
#pragma unroll
      for (int js = 0; js < 8; ++js)
        d += x[js * STR + (size_t)(r0 + t) * 160 + 128];
      degs[t] = d;
    }
    __syncthreads();
    for (int i = t; i < 16 * DIN; i += 256) {
      int r = i / DIN, c = i % DIN;
      float s = 0.f;
#pragma unroll
      for (int js = 0; js < 8; ++js)
        s += x[js * STR + (size_t)(r0 + r) * 160 + c];
      xs[r][c] = fmaxf(s, 0.f) / degs[r];
    }
  } else {
    for (int i = t; i < 16 * DIN; i += 256)
      xs[i / DIN][i % DIN] = x[(size_t)(r0 + i / DIN) * DIN + (i % DIN)];
  }
  if (t < 16) sqs[t] = 0.f;
  __syncthreads();

  // A-frags: lane(g,q) elem e = bf16(xs[q][32kk+8g+e])
  bf16x8 aF[KKD];
#pragma unroll
  for (int kk = 0; kk < KKD; ++kk) {
    const float* src = &xs[q][32 * kk + 8 * g];
    __align__(16) ushort_t tmp[8];
#pragma unroll
    for (int e = 0; e < 8; ++e) tmp[e] = f2bf(src[e]);
    aF[kk] = *(const bf16x8*)tmp;
  }
  f32x4 acc[NCTW];
#pragma unroll
  for (int tl = 0; tl < NCTW; ++tl) {
    int c = 16 * (NCTW * w + tl) + q;
    float bv = (c < F) ? b1[c] : b2[c - F];
    acc[tl] = (f32x4){bv, bv, bv, bv};
  }
#pragma unroll
  for (int kk = 0; kk < KKD; ++kk)
#pragma unroll
    for (int tl = 0; tl < NCTW; ++tl) {
      bf16x8 bW = *(const bf16x8*)(Wf +
          ((size_t)(kk * NCT) + (NCTW * w + tl)) * 512 + lane * 8);
      acc[tl] = __builtin_amdgcn_mfma_f32_16x16x32_bf16(aF[kk], bW, acc[tl], 0, 0, 0);
    }
#pragma unroll
  for (int tl = 0; tl < NCTW; ++tl)
#pragma unroll
    for (int r = 0; r < 4; ++r) {
      int row = 4 * g + r, c = 16 * (NCTW * w + tl) + q;
      float v = acc[tl][r];
      if (c < F) {
        float gv = fmaxf(v, 0.f);
        ushort_t gb = f2bf(gv);
        gls[row][c] = gb;
        float gf = bf2f(gb);
        atomicAdd(&sqs[row], gf * gf);
      } else {
        hs[row][c - F] = v;
      }
    }
  __syncthreads();
  if (t < 16) sq[r0 + t] = sqs[t];

  // ---- glf32 writer: block rows are half a 32-row tile (halves by m&1)
  if (t < 32 * (F / 16)) {
    int ch = t >> 5, li = t & 31;
    int lane2 = 32 * (li >> 4) + 16 * (m & 1) + (li & 15);
    const uint4* src = (const uint4*)&gls[li & 15][16 * ch + 8 * (li >> 4)];
    *(uint4*)(glf32 + ((size_t)(m >> 1) * (F / 16) + ch) * 512 + lane2 * 8) = *src;
  }
  // ---- hf32 writer: block = one 16-j window (jw = m)
  if (t < FT * 64) {
    int ft = t >> 6, l2 = t & 63;
    __align__(16) ushort_t tmp[8];
#pragma unroll
    for (int e = 0; e < 8; ++e)
      tmp[e] = f2bf(hs[8 * (l2 >> 5) + e][32 * ft + (l2 & 31)]);
    *(uint4*)(hf32 + ((size_t)m * FT + ft) * 512 + l2 * 8) = *(const uint4*)tmp;
  }
}

// ---------------------------------------------------------------------------
// fused (R19): 32x32 MFMA, NO adj LDS, NO fences. Per 32-j window:
//  S^T = mfma_32x32x16(A=gl_j, B=gl_i) over K=F  (D: i=lane&31, j=reg-map)
//  -> sigmoid in-register (sqi = scalar/lane) -> cvt_pk + permlane32_swap
//  assembles PV A-frags -> acc[ft] += mfma_32x32x16(PA, hf32) (ones tile =
//  deg col). Two barriers/iter only. partial row stride = 32*(FT+1).
// ---------------------------------------------------------------------------
template<int F>
__global__ __launch_bounds__(256) void fused_kernel(
    const ushort_t* __restrict__ glf32, const float* __restrict__ sq,
    const ushort_t* __restrict__ hf32,
    const float* __restrict__ temp_p, const float* __restrict__ theta_p,
    float* __restrict__ partial)
{
  constexpr int FT   = F / 32;        // real f-tiles (4 / 2)
  constexpr int FpO  = 32 * (FT + 1); // partial stride (160 / 96)
  constexpr int KKW  = F / 16;        // phase-A K-fragments (8 / 4)
  constexpr int JS   = 8;
  constexpr int JCH  = NROWS / JS;
  constexpr int NIT  = JCH / 32;
  constexpr int NCHB = KKW;           // j-frag chunks per window
  constexpr int NCH  = NCHB + 2 * FT; // + h chunks (2 jw x FT)
  constexpr float EPS = 1.1920929e-07f;
  constexpr float LOG2E = 1.4426950408889634f;
  __shared__ __align__(16) ushort_t stage[NCH * 512 + 128];  // 16.25KB / 8.25KB

  const int w = threadIdx.x >> 6, lane = threadIdx.x & 63;
  const int hi = lane >> 5, col = lane & 31;
  const int n  = blockIdx.x + (int)gridDim.x * blockIdx.y;
  const int bx = n >> 3, by = n & 7;        // XCD-bijective (512 = 8*64)
  const int irow  = bx * 128 + 32 * w;      // wave's 32 i-rows
  const int jbase = by * JCH;
  const float c1 = 1.0f + *temp_p;
  const float c0 = 5.0f + *theta_p;
  const float k1 = c1 * LOG2E;
  const float k0 = -c0 * LOG2E;

  // hoist i-side fragments (B operand) + per-lane sqi
  bf16x8 iF[KKW];
#pragma unroll
  for (int kk = 0; kk < KKW; ++kk)
    iF[kk] = *(const bf16x8*)(glf32 +
        ((size_t)(irow >> 5) * KKW + kk) * 512 + lane * 8);
  const float sqi = sq[irow + col] + EPS;

  // ones f-tile (deg col = first col of tile FT)
  bf16x8 onesF;
  {
    __align__(16) ushort_t tmp[8];
    ushort_t v = (col == 0) ? (ushort_t)0x3F80 : (ushort_t)0;
#pragma unroll
    for (int e = 0; e < 8; ++e) tmp[e] = v;
    onesF = *(const bf16x8*)tmp;
  }

  f32x16 acc[FT + 1];
#pragma unroll
  for (int ft = 0; ft <= FT; ++ft)
#pragma unroll
    for (int r = 0; r < 16; ++r) acc[ft][r] = 0.f;

  const float* sqlane = (const float*)(stage + NCH * 512) + 4 * hi;

#pragma unroll 1
  for (int k = 0; k < NIT; ++k) {
    const int j0 = jbase + k * 32;
    __syncthreads();   // WAR: all waves done reading stage
    {
      const ushort_t* glB = glf32 + (size_t)(j0 >> 5) * KKW * 512;
      const ushort_t* glH = hf32  + (size_t)(j0 >> 4) * FT * 512;
#pragma unroll
      for (int ch = w; ch < NCH; ch += 4) {
        const ushort_t* src = (ch < NCHB) ? (glB + (size_t)ch * 512)
                                          : (glH + (size_t)(ch - NCHB) * 512);
        load_lds16(src + lane * 8, stage + ch * 512);
      }
      if (w == 3 && lane < 32)
        load_lds4(sq + j0 + lane, (float*)(stage + NCH * 512) + lane);
    }
    __syncthreads();   // drains vmcnt + barrier

    // ---- phase A: S^T tile, K=F chain of 32x32x16
    f32x16 sacc;
#pragma unroll
    for (int r = 0; r < 16; ++r) sacc[r] = 0.f;
#pragma unroll
    for (int kk = 0; kk < KKW; ++kk) {
      bf16x8 jf = *(const bf16x8*)(stage + kk * 512 + lane * 8);
      sacc = __builtin_amdgcn_mfma_f32_32x32x16_bf16(jf, iF[kk], sacc, 0, 0, 0);
    }
    // ---- sqj: 4 vector reads from staged sq (j = 8G + 4hi + 0..3)
    f32x4 sqjv[4];
#pragma unroll
    for (int G = 0; G < 4; ++G) sqjv[G] = *(const f32x4*)(sqlane + 8 * G);
    // ---- elementwise sigmoid, 16 regs
    float adjv[16];
#pragma unroll
    for (int r = 0; r < 16; ++r) {
      float t1 = sqi + sqjv[r >> 2][r & 3];
      float d  = fmaxf(fmaf(-2.f, sacc[r], t1), EPS);
      float e  = __builtin_amdgcn_exp2f(fmaf(k1, __builtin_amdgcn_sqrtf(d), k0));
      adjv[r] = __builtin_amdgcn_rcpf(1.f + e);
    }
    // ---- pack to PV A-frags: cvt_pk pairs + permlane32_swap half-exchange
    uint_t P0 = cvtpk(adjv[0],  adjv[1]),  P1 = cvtpk(adjv[2],  adjv[3]);
    uint_t P2 = cvtpk(adjv[4],  adjv[5]),  P3 = cvtpk(adjv[6],  adjv[7]);
    uint_t P4 = cvtpk(adjv[8],  adjv[9]),  P5 = cvtpk(adjv[10], adjv[11]);
    uint_t P6 = cvtpk(adjv[12], adjv[13]), P7 = cvtpk(adjv[14], adjv[15]);
    u32x2 sA0 = __builtin_amdgcn_permlane32_swap(P2, P0, false, false);
    u32x2 sA1 = __builtin_amdgcn_permlane32_swap(P3, P1, false, false);
    u32x2 sB0 = __builtin_amdgcn_permlane32_swap(P6, P4, false, false);
    u32x2 sB1 = __builtin_amdgcn_permlane32_swap(P7, P5, false, false);
    u32x4 dw1 = {sA0[1], sA1[1], sA0[0], sA1[0]};   // j 0..15 window
    u32x4 dw2 = {sB0[1], sB1[1], sB0[0], sB1[0]};   // j 16..31 window
    bf16x8 PA1 = __builtin_bit_cast(bf16x8, dw1);
    bf16x8 PA2 = __builtin_bit_cast(bf16x8, dw2);
    // ---- PV: acc[ft] += adj @ h over two K=16 windows
#pragma unroll
    for (int o = 0; o < 2; ++o) {
      bf16x8 PA = o ? PA2 : PA1;
#pragma unroll
      for (int ft = 0; ft <= FT; ++ft) {
        bf16x8 hfr = (ft == FT)
            ? onesF
            : *(const bf16x8*)(stage + (NCHB + o * FT + ft) * 512 + lane * 8);
        acc[ft] = __builtin_amdgcn_mfma_f32_32x32x16_bf16(PA, hfr, acc[ft], 0, 0, 0);
      }
    }
  }

  // ---- epilogue: D rows = i = (r&3)+8(r>>2)+4hi; cols = 32ft+col
  float* op = partial + ((size_t)by * NROWS + irow) * FpO + col;
#pragma unroll
  for (int ft = 0; ft <= FT; ++ft)
#pragma unroll
    for (int r = 0; r < 16; ++r) {
      int row = (r & 3) + 8 * (r >> 2) + 4 * hi;
      op[(size_t)row * FpO + 32 * ft] = acc[ft][r];
    }
}

// out = softmax(sum_js(partial)/deg); partial stride 96, deg col 64
__global__ __launch_bounds__(256) void reduce_softmax_kernel(
    const float* __restrict__ partial, float* __restrict__ out)
{
  int t = threadIdx.x;
  int r = blockIdx.x * 4 + (t >> 6), c = t & 63;
  size_t base = (size_t)r * 96;
  size_t stride = (size_t)NROWS * 96;
  float v = 0.f, d = 0.f;
#pragma unroll
  for (int js = 0; js < 8; ++js) {
    v += partial[js * stride + base + c];
    d += partial[js * stride + base + 64];
  }
  v /= d;
  float m = v;
  for (int o = 32; o > 0; o >>= 1) m = fmaxf(m, __shfl_xor(m, o, 64));
  float e = __expf(v - m);
  float s = e;
  for (int o = 32; o > 0; o >>= 1) s += __shfl_xor(s, o, 64);
  out[(size_t)r * 64 + c] = e / s;
}

extern "C" void kernel_launch(void* const* d_in, const int* in_sizes, int n_in,
                              void* d_out, int out_size, void* d_ws, size_t ws_size,
                              hipStream_t stream) {
  const float* feat  = (const float*)d_in[0];
  const float* Wgl0  = (const float*)d_in[6];
  const float* bgl0  = (const float*)d_in[7];
  const float* Wgnn0 = (const float*)d_in[8];
  const float* bgnn0 = (const float*)d_in[9];
  const float* Wgl1  = (const float*)d_in[10];
  const float* bgl1  = (const float*)d_in[11];
  const float* Wgnn1 = (const float*)d_in[12];
  const float* bgnn1 = (const float*)d_in[13];
  const float* temp  = (const float*)d_in[14];
  const float* theta = (const float*)d_in[15];
  float* out = (float*)d_out;

  char* ws = (char*)d_ws;
  size_t off = 0;
  auto alloc = [&](size_t bytes) {
    char* p = ws + off;
    off = (off + bytes + 255) & ~(size_t)255;
    return p;
  };
  float*    par0 = (float*)alloc(8ull * NROWS * 160 * 4);  // 41.9 MB
  float*    par1 = par0;  // aliased: par0 fully consumed by lin1 first
  ushort_t* glf0 = (ushort_t*)alloc((8192ull / 32) * 8 * 512 * 2);  // 2 MB
  ushort_t* glf1 = (ushort_t*)alloc((8192ull / 32) * 4 * 512 * 2);  // 1 MB
  ushort_t* hf0  = (ushort_t*)alloc((8192ull / 16) * 4 * 512 * 2);  // 2 MB
  ushort_t* hf1  = (ushort_t*)alloc((8192ull / 16) * 2 * 512 * 2);  // 1 MB
  float*    sq0  = (float*)alloc(8192ull * 4);
  float*    sq1  = (float*)alloc(8192ull * 4);
  ushort_t* Wf0  = (ushort_t*)alloc(8ull * 16 * 512 * 2);   // 128 KB
  ushort_t* Wf1  = (ushort_t*)alloc(4ull * 8 * 512 * 2);    // 32 KB

  prep_w_kernel<256, 128><<<256, 256, 0, stream>>>(Wgl0, Wgnn0, Wf0);
  prep_w_kernel<128, 64><<<64, 256, 0, stream>>>(Wgl1, Wgnn1, Wf1);

  lin_kernel<256, 128, false><<<512, 256, 0, stream>>>(feat, Wf0, bgl0, bgnn0, glf0, sq0, hf0);
  fused_kernel<128><<<dim3(64, 8), 256, 0, stream>>>(glf0, sq0, hf0, temp, theta, par0);

  lin_kernel<128, 64, true><<<512, 256, 0, stream>>>(par0, Wf1, bgl1, bgnn1, glf1, sq1, hf1);
  fused_kernel<64><<<dim3(64, 8), 256, 0, stream>>>(glf1, sq1, hf1, temp, theta, par1);
  reduce_softmax_kernel<<<2048, 256, 0, stream>>>(par1, out);
}

// Round 20
// 140.667 us; speedup vs baseline: 1.0614x; 1.0431x over previous
//
#include <hip/hip_runtime.h>
#include <hip/hip_bf16.h>

#define NROWS 8192

typedef __bf16 bf16x8 __attribute__((ext_vector_type(8)));
typedef float f32x4 __attribute__((ext_vector_type(4)));
typedef float f32x16 __attribute__((ext_vector_type(16)));
typedef unsigned int u32x2 __attribute__((ext_vector_type(2)));
typedef unsigned int u32x4 __attribute__((ext_vector_type(4)));
typedef unsigned short ushort_t;
typedef unsigned int uint_t;

__device__ __forceinline__ ushort_t f2bf(float f) {
  uint_t u = __builtin_bit_cast(uint_t, f);
  u += 0x7fffu + ((u >> 16) & 1u);   // round-to-nearest-even
  return (ushort_t)(u >> 16);
}
__device__ __forceinline__ float bf2f(ushort_t h) {
  uint_t u = ((uint_t)h) << 16;
  return __builtin_bit_cast(float, u);
}
// pack two f32 -> dword of 2 bf16 (lo = first arg)
__device__ __forceinline__ uint_t cvtpk(float lo, float hi) {
  uint_t r;
  asm("v_cvt_pk_bf16_f32 %0, %1, %2" : "=v"(r) : "v"(lo), "v"(hi));
  return r;
}
// async global->LDS DMA; LDS dest = uniform base + lane*size
__device__ __forceinline__ void load_lds16(const ushort_t* g, ushort_t* l) {
  __builtin_amdgcn_global_load_lds(
      (const __attribute__((address_space(1))) unsigned int*)g,
      (__attribute__((address_space(3))) unsigned int*)l, 16, 0, 0);
}
__device__ __forceinline__ void load_lds4(const float* g, float* l) {
  __builtin_amdgcn_global_load_lds(
      (const __attribute__((address_space(1))) unsigned int*)g,
      (__attribute__((address_space(3))) unsigned int*)l, 4, 0, 0);
}

// ---------------------------------------------------------------------------
// prep_w: pack Wcat=[W1|W2] (fp32) into fragment-major bf16 Wf (16x16 frags).
// ---------------------------------------------------------------------------
template<int DIN, int F>
__global__ __launch_bounds__(256) void prep_w_kernel(
    const float* __restrict__ W1, const float* __restrict__ W2,
    ushort_t* __restrict__ Wf)
{
  constexpr int NCT = (2 * F) / 16;
  int idx = blockIdx.x * 256 + threadIdx.x;   // grid sized exactly
  int e = idx & 7, lane = (idx >> 3) & 63;
  int ct = (idx >> 9) % NCT, kk = (idx >> 9) / NCT;
  int g = lane >> 4, q = lane & 15;
  int k = 32 * kk + 8 * g + e, c = 16 * ct + q;
  float v = (c < F) ? W1[(size_t)k * F + c] : W2[(size_t)k * F + (c - F)];
  Wf[idx] = f2bf(v);
}

// ---------------------------------------------------------------------------
// lin (R20 = R19): MFMA GEMM for [gl|h] = x @ [W1|W2] + b. RED=true: x
// produced inline from the 8 partial slabs (stride 160). Writers emit
// 32x32-fragment-major glf32 / hf32 and sq (see R19 comments).
// ---------------------------------------------------------------------------
template<int DIN, int F, bool RED>
__global__ __launch_bounds__(256) void lin_kernel(
    const float* __restrict__ x, const ushort_t* __restrict__ Wf,
    const float* __restrict__ b1, const float* __restrict__ b2,
    ushort_t* __restrict__ glf32, float* __restrict__ sq, ushort_t* __restrict__ hf32)
{
  constexpr int KKD  = DIN / 32;     // GEMM K-fragments
  constexpr int NCT  = (2 * F) / 16; // output col-tiles (gl|h)
  constexpr int NCTW = NCT / 4;      // col-tiles per wave
  constexpr int FT   = F / 32;       // hf32 real f-tiles
  __shared__ float    xs[16][DIN];
  __shared__ float    hs[16][F];
  __shared__ ushort_t gls[16][F];
  __shared__ float    sqs[16];
  __shared__ float    degs[16];
  const int t  = threadIdx.x;
  const int m  = blockIdx.x;
  const int r0 = m * 16;
  const int w = t >> 6, lane = t & 63, g = lane >> 4, q = lane & 15;

  if (RED) {
    constexpr size_t STR = (size_t)NROWS * 160;
    if (t < 16) {
      float d = 0.f;
#pragma unroll
      for (int js = 0; js < 8; ++js)
        d += x[js * STR + (size_t)(r0 + t) * 160 + 128];
      degs[t] = d;
    }
    __syncthreads();
    for (int i = t; i < 16 * DIN; i += 256) {
      int r = i / DIN, c = i % DIN;
      float s = 0.f;
#pragma unroll
      for (int js = 0; js < 8; ++js)
        s += x[js * STR + (size_t)(r0 + r) * 160 + c];
      xs[r][c] = fmaxf(s, 0.f) / degs[r];
    }
  } else {
    for (int i = t; i < 16 * DIN; i += 256)
      xs[i / DIN][i % DIN] = x[(size_t)(r0 + i / DIN) * DIN + (i % DIN)];
  }
  if (t < 16) sqs[t] = 0.f;
  __syncthreads();

  bf16x8 aF[KKD];
#pragma unroll
  for (int kk = 0; kk < KKD; ++kk) {
    const float* src = &xs[q][32 * kk + 8 * g];
    __align__(16) ushort_t tmp[8];
#pragma unroll
    for (int e = 0; e < 8; ++e) tmp[e] = f2bf(src[e]);
    aF[kk] = *(const bf16x8*)tmp;
  }
  f32x4 acc[NCTW];
#pragma unroll
  for (int tl = 0; tl < NCTW; ++tl) {
    int c = 16 * (NCTW * w + tl) + q;
    float bv = (c < F) ? b1[c] : b2[c - F];
    acc[tl] = (f32x4){bv, bv, bv, bv};
  }
#pragma unroll
  for (int kk = 0; kk < KKD; ++kk)
#pragma unroll
    for (int tl = 0; tl < NCTW; ++tl) {
      bf16x8 bW = *(const bf16x8*)(Wf +
          ((size_t)(kk * NCT) + (NCTW * w + tl)) * 512 + lane * 8);
      acc[tl] = __builtin_amdgcn_mfma_f32_16x16x32_bf16(aF[kk], bW, acc[tl], 0, 0, 0);
    }
#pragma unroll
  for (int tl = 0; tl < NCTW; ++tl)
#pragma unroll
    for (int r = 0; r < 4; ++r) {
      int row = 4 * g + r, c = 16 * (NCTW * w + tl) + q;
      float v = acc[tl][r];
      if (c < F) {
        float gv = fmaxf(v, 0.f);
        ushort_t gb = f2bf(gv);
        gls[row][c] = gb;
        float gf = bf2f(gb);
        atomicAdd(&sqs[row], gf * gf);
      } else {
        hs[row][c - F] = v;
      }
    }
  __syncthreads();
  if (t < 16) sq[r0 + t] = sqs[t];

  // ---- glf32 writer: block rows are half a 32-row tile (halves by m&1)
  if (t < 32 * (F / 16)) {
    int ch = t >> 5, li = t & 31;
    int lane2 = 32 * (li >> 4) + 16 * (m & 1) + (li & 15);
    const uint4* src = (const uint4*)&gls[li & 15][16 * ch + 8 * (li >> 4)];
    *(uint4*)(glf32 + ((size_t)(m >> 1) * (F / 16) + ch) * 512 + lane2 * 8) = *src;
  }
  // ---- hf32 writer: block = one 16-j window (jw = m)
  if (t < FT * 64) {
    int ft = t >> 6, l2 = t & 63;
    __align__(16) ushort_t tmp[8];
#pragma unroll
    for (int e = 0; e < 8; ++e)
      tmp[e] = f2bf(hs[8 * (l2 >> 5) + e][32 * ft + (l2 & 31)]);
    *(uint4*)(hf32 + ((size_t)m * FT + ft) * 512 + l2 * 8) = *(const uint4*)tmp;
  }
}

// ---------------------------------------------------------------------------
// fused (R20 = R19 + 64-j iterations, dual independent chains): per iter
// stage a 64-j window (two contiguous regions + one 64-lane sq load), run
// TWO independent S^T MFMA chains (windows A/B) -> two sigmoid/pack streams
// -> PV over 4 K=16 sub-windows. Halves barrier count and L2-latency
// exposures; doubles independent work per barrier quantum (the R19 post-
// mortem's diagnosis: chain-latency-bound at 2 waves/SIMD).
// ---------------------------------------------------------------------------
template<int F>
__global__ __launch_bounds__(256) void fused_kernel(
    const ushort_t* __restrict__ glf32, const float* __restrict__ sq,
    const ushort_t* __restrict__ hf32,
    const float* __restrict__ temp_p, const float* __restrict__ theta_p,
    float* __restrict__ partial)
{
  constexpr int FT   = F / 32;        // real f-tiles (4 / 2)
  constexpr int FpO  = 32 * (FT + 1); // partial stride (160 / 96)
  constexpr int KKW  = F / 16;        // phase-A K-fragments per window (8/4)
  constexpr int JS   = 8;
  constexpr int JCH  = NROWS / JS;
  constexpr int NIT  = JCH / 64;      // 16 iterations of 64 j's
  constexpr int NCHT = 2 * KKW + 4 * FT;  // staged chunks (32 / 16)
  constexpr float EPS = 1.1920929e-07f;
  constexpr float LOG2E = 1.4426950408889634f;
  __shared__ __align__(16) ushort_t stage[NCHT * 512 + 128];  // 33KB / 16.6KB

  const int w = threadIdx.x >> 6, lane = threadIdx.x & 63;
  const int hi = lane >> 5, col = lane & 31;
  const int n  = blockIdx.x + (int)gridDim.x * blockIdx.y;
  const int bx = n >> 3, by = n & 7;        // XCD-bijective (512 = 8*64)
  const int irow  = bx * 128 + 32 * w;      // wave's 32 i-rows
  const int jbase = by * JCH;
  const float c1 = 1.0f + *temp_p;
  const float c0 = 5.0f + *theta_p;
  const float k1 = c1 * LOG2E;
  const float k0 = -c0 * LOG2E;

  // hoist i-side fragments (B operand) + per-lane sqi
  bf16x8 iF[KKW];
#pragma unroll
  for (int kk = 0; kk < KKW; ++kk)
    iF[kk] = *(const bf16x8*)(glf32 +
        ((size_t)(irow >> 5) * KKW + kk) * 512 + lane * 8);
  const float sqi = sq[irow + col] + EPS;

  // ones f-tile (deg col = first col of tile FT)
  bf16x8 onesF;
  {
    __align__(16) ushort_t tmp[8];
    ushort_t v = (col == 0) ? (ushort_t)0x3F80 : (ushort_t)0;
#pragma unroll
    for (int e = 0; e < 8; ++e) tmp[e] = v;
    onesF = *(const bf16x8*)tmp;
  }

  f32x16 acc[FT + 1];
#pragma unroll
  for (int ft = 0; ft <= FT; ++ft)
#pragma unroll
    for (int r = 0; r < 16; ++r) acc[ft][r] = 0.f;

  const float* sqslot = (const float*)(stage + NCHT * 512);

#pragma unroll 1
  for (int k = 0; k < NIT; ++k) {
    const int j0 = jbase + k * 64;
    __syncthreads();   // WAR: all waves done reading stage
    {
      // two contiguous regions: 2*KKW j-frag chunks, 4*FT h chunks
      const ushort_t* glB = glf32 + (size_t)(j0 >> 5) * KKW * 512;
      const ushort_t* glH = hf32  + (size_t)(j0 >> 4) * FT * 512;
#pragma unroll
      for (int ch = w; ch < NCHT; ch += 4) {
        const ushort_t* src = (ch < 2 * KKW)
            ? (glB + (size_t)ch * 512)
            : (glH + (size_t)(ch - 2 * KKW) * 512);
        load_lds16(src + lane * 8, stage + ch * 512);
      }
      if (w == 3)   // one 64-lane load covers sq[j0..j0+63]
        load_lds4(sq + j0 + lane, (float*)sqslot + lane);
    }
    __syncthreads();   // drains vmcnt + barrier

    // ---- phase A: TWO independent S^T chains (windows A = j0, B = j0+32)
    f32x16 saccA, saccB;
#pragma unroll
    for (int r = 0; r < 16; ++r) { saccA[r] = 0.f; saccB[r] = 0.f; }
#pragma unroll
    for (int kk = 0; kk < KKW; ++kk) {
      bf16x8 jfA = *(const bf16x8*)(stage + kk * 512 + lane * 8);
      bf16x8 jfB = *(const bf16x8*)(stage + (KKW + kk) * 512 + lane * 8);
      saccA = __builtin_amdgcn_mfma_f32_32x32x16_bf16(jfA, iF[kk], saccA, 0, 0, 0);
      saccB = __builtin_amdgcn_mfma_f32_32x32x16_bf16(jfB, iF[kk], saccB, 0, 0, 0);
    }
    // ---- per-window: sigmoid -> pack -> PV (two K=16 sub-windows each)
#pragma unroll
    for (int W = 0; W < 2; ++W) {
      const f32x16& sacc = W ? saccB : saccA;
      const float* sqlane = sqslot + 32 * W + 4 * hi;
      f32x4 sqjv[4];
#pragma unroll
      for (int G = 0; G < 4; ++G) sqjv[G] = *(const f32x4*)(sqlane + 8 * G);
      float adjv[16];
#pragma unroll
      for (int r = 0; r < 16; ++r) {
        float t1 = sqi + sqjv[r >> 2][r & 3];
        float d  = fmaxf(fmaf(-2.f, sacc[r], t1), EPS);
        float e  = __builtin_amdgcn_exp2f(fmaf(k1, __builtin_amdgcn_sqrtf(d), k0));
        adjv[r] = __builtin_amdgcn_rcpf(1.f + e);
      }
      uint_t P0 = cvtpk(adjv[0],  adjv[1]),  P1 = cvtpk(adjv[2],  adjv[3]);
      uint_t P2 = cvtpk(adjv[4],  adjv[5]),  P3 = cvtpk(adjv[6],  adjv[7]);
      uint_t P4 = cvtpk(adjv[8],  adjv[9]),  P5 = cvtpk(adjv[10], adjv[11]);
      uint_t P6 = cvtpk(adjv[12], adjv[13]), P7 = cvtpk(adjv[14], adjv[15]);
      u32x2 sA0 = __builtin_amdgcn_permlane32_swap(P2, P0, false, false);
      u32x2 sA1 = __builtin_amdgcn_permlane32_swap(P3, P1, false, false);
      u32x2 sB0 = __builtin_amdgcn_permlane32_swap(P6, P4, false, false);
      u32x2 sB1 = __builtin_amdgcn_permlane32_swap(P7, P5, false, false);
      u32x4 dw1 = {sA0[1], sA1[1], sA0[0], sA1[0]};   // j-sub 0..15
      u32x4 dw2 = {sB0[1], sB1[1], sB0[0], sB1[0]};   // j-sub 16..31
      bf16x8 PA1 = __builtin_bit_cast(bf16x8, dw1);
      bf16x8 PA2 = __builtin_bit_cast(bf16x8, dw2);
#pragma unroll
      for (int o2 = 0; o2 < 2; ++o2) {
        int o = 2 * W + o2;               // global K=16 sub-window 0..3
        bf16x8 PA = o2 ? PA2 : PA1;
#pragma unroll
        for (int ft = 0; ft <= FT; ++ft) {
          bf16x8 hfr = (ft == FT)
              ? onesF
              : *(const bf16x8*)(stage + (2 * KKW + o * FT + ft) * 512 + lane * 8);
          acc[ft] = __builtin_amdgcn_mfma_f32_32x32x16_bf16(PA, hfr, acc[ft], 0, 0, 0);
        }
      }
    }
  }

  // ---- epilogue: D rows = i = (r&3)+8(r>>2)+4hi; cols = 32ft+col
  float* op = partial + ((size_t)by * NROWS + irow) * FpO + col;
#pragma unroll
  for (int ft = 0; ft <= FT; ++ft)
#pragma unroll
    for (int r = 0; r < 16; ++r) {
      int row = (r & 3) + 8 * (r >> 2) + 4 * hi;
      op[(size_t)row * FpO + 32 * ft] = acc[ft][r];
    }
}

// out = softmax(sum_js(partial)/deg); partial stride 96, deg col 64
__global__ __launch_bounds__(256) void reduce_softmax_kernel(
    const float* __restrict__ partial, float* __restrict__ out)
{
  int t = threadIdx.x;
  int r = blockIdx.x * 4 + (t >> 6), c = t & 63;
  size_t base = (size_t)r * 96;
  size_t stride = (size_t)NROWS * 96;
  float v = 0.f, d = 0.f;
#pragma unroll
  for (int js = 0; js < 8; ++js) {
    v += partial[js * stride + base + c];
    d += partial[js * stride + base + 64];
  }
  v /= d;
  float m = v;
  for (int o = 32; o > 0; o >>= 1) m = fmaxf(m, __shfl_xor(m, o, 64));
  float e = __expf(v - m);
  float s = e;
  for (int o = 32; o > 0; o >>= 1) s += __shfl_xor(s, o, 64);
  out[(size_t)r * 64 + c] = e / s;
}

extern "C" void kernel_launch(void* const* d_in, const int* in_sizes, int n_in,
                              void* d_out, int out_size, void* d_ws, size_t ws_size,
                              hipStream_t stream) {
  const float* feat  = (const float*)d_in[0];
  const float* Wgl0  = (const float*)d_in[6];
  const float* bgl0  = (const float*)d_in[7];
  const float* Wgnn0 = (const float*)d_in[8];
  const float* bgnn0 = (const float*)d_in[9];
  const float* Wgl1  = (const float*)d_in[10];
  const float* bgl1  = (const float*)d_in[11];
  const float* Wgnn1 = (const float*)d_in[12];
  const float* bgnn1 = (const float*)d_in[13];
  const float* temp  = (const float*)d_in[14];
  const float* theta = (const float*)d_in[15];
  float* out = (float*)d_out;

  char* ws = (char*)d_ws;
  size_t off = 0;
  auto alloc = [&](size_t bytes) {
    char* p = ws + off;
    off = (off + bytes + 255) & ~(size_t)255;
    return p;
  };
  float*    par0 = (float*)alloc(8ull * NROWS * 160 * 4);  // 41.9 MB
  float*    par1 = par0;  // aliased: par0 fully consumed by lin1 first
  ushort_t* glf0 = (ushort_t*)alloc((8192ull / 32) * 8 * 512 * 2);  // 2 MB
  ushort_t* glf1 = (ushort_t*)alloc((8192ull / 32) * 4 * 512 * 2);  // 1 MB
  ushort_t* hf0  = (ushort_t*)alloc((8192ull / 16) * 4 * 512 * 2);  // 2 MB
  ushort_t* hf1  = (ushort_t*)alloc((8192ull / 16) * 2 * 512 * 2);  // 1 MB
  float*    sq0  = (float*)alloc(8192ull * 4);
  float*    sq1  = (float*)alloc(8192ull * 4);
  ushort_t* Wf0  = (ushort_t*)alloc(8ull * 16 * 512 * 2);   // 128 KB
  ushort_t* Wf1  = (ushort_t*)alloc(4ull * 8 * 512 * 2);    // 32 KB

  prep_w_kernel<256, 128><<<256, 256, 0, stream>>>(Wgl0, Wgnn0, Wf0);
  prep_w_kernel<128, 64><<<64, 256, 0, stream>>>(Wgl1, Wgnn1, Wf1);

  lin_kernel<256, 128, false><<<512, 256, 0, stream>>>(feat, Wf0, bgl0, bgnn0, glf0, sq0, hf0);
  fused_kernel<128><<<dim3(64, 8), 256, 0, stream>>>(glf0, sq0, hf0, temp, theta, par0);

  lin_kernel<128, 64, true><<<512, 256, 0, stream>>>(par0, Wf1, bgl1, bgnn1, glf1, sq1, hf1);
  fused_kernel<64><<<dim3(64, 8), 256, 0, stream>>>(glf1, sq1, hf1, temp, theta, par1);
  reduce_softmax_kernel<<<2048, 256, 0, stream>>>(par1, out);
}

// Round 21
// 137.093 us; speedup vs baseline: 1.0891x; 1.0261x over previous
//
#include <hip/hip_runtime.h>
#include <hip/hip_bf16.h>

#define NROWS 8192

typedef __bf16 bf16x8 __attribute__((ext_vector_type(8)));
typedef float f32x4 __attribute__((ext_vector_type(4)));
typedef float f32x16 __attribute__((ext_vector_type(16)));
typedef unsigned int u32x2 __attribute__((ext_vector_type(2)));
typedef unsigned int u32x4 __attribute__((ext_vector_type(4)));
typedef unsigned short ushort_t;
typedef unsigned int uint_t;

__device__ __forceinline__ ushort_t f2bf(float f) {
  uint_t u = __builtin_bit_cast(uint_t, f);
  u += 0x7fffu + ((u >> 16) & 1u);   // round-to-nearest-even
  return (ushort_t)(u >> 16);
}
__device__ __forceinline__ float bf2f(ushort_t h) {
  uint_t u = ((uint_t)h) << 16;
  return __builtin_bit_cast(float, u);
}
// pack two f32 -> dword of 2 bf16 (lo = first arg)
__device__ __forceinline__ uint_t cvtpk(float lo, float hi) {
  uint_t r;
  asm("v_cvt_pk_bf16_f32 %0, %1, %2" : "=v"(r) : "v"(lo), "v"(hi));
  return r;
}
// async global->LDS DMA; LDS dest = uniform base + lane*size
__device__ __forceinline__ void load_lds16(const ushort_t* g, ushort_t* l) {
  __builtin_amdgcn_global_load_lds(
      (const __attribute__((address_space(1))) unsigned int*)g,
      (__attribute__((address_space(3))) unsigned int*)l, 16, 0, 0);
}
__device__ __forceinline__ void load_lds4(const float* g, float* l) {
  __builtin_amdgcn_global_load_lds(
      (const __attribute__((address_space(1))) unsigned int*)g,
      (__attribute__((address_space(3))) unsigned int*)l, 4, 0, 0);
}

// ---------------------------------------------------------------------------
// prep_w: pack Wcat=[W1|W2] (fp32) into fragment-major bf16 Wf (16x16 frags).
// ---------------------------------------------------------------------------
template<int DIN, int F>
__global__ __launch_bounds__(256) void prep_w_kernel(
    const float* __restrict__ W1, const float* __restrict__ W2,
    ushort_t* __restrict__ Wf)
{
  constexpr int NCT = (2 * F) / 16;
  int idx = blockIdx.x * 256 + threadIdx.x;   // grid sized exactly
  int e = idx & 7, lane = (idx >> 3) & 63;
  int ct = (idx >> 9) % NCT, kk = (idx >> 9) / NCT;
  int g = lane >> 4, q = lane & 15;
  int k = 32 * kk + 8 * g + e, c = 16 * ct + q;
  float v = (c < F) ? W1[(size_t)k * F + c] : W2[(size_t)k * F + (c - F)];
  Wf[idx] = f2bf(v);
}

// ---------------------------------------------------------------------------
// lin (R21 = R19): MFMA GEMM for [gl|h] = x @ [W1|W2] + b. RED=true: x
// produced inline from the 8 partial slabs (stride 160). Writers emit
// 32x32-fragment-major glf32 / hf32 and sq.
// ---------------------------------------------------------------------------
template<int DIN, int F, bool RED>
__global__ __launch_bounds__(256) void lin_kernel(
    const float* __restrict__ x, const ushort_t* __restrict__ Wf,
    const float* __restrict__ b1, const float* __restrict__ b2,
    ushort_t* __restrict__ glf32, float* __restrict__ sq, ushort_t* __restrict__ hf32)
{
  constexpr int KKD  = DIN / 32;     // GEMM K-fragments
  constexpr int NCT  = (2 * F) / 16; // output col-tiles (gl|h)
  constexpr int NCTW = NCT / 4;      // col-tiles per wave
  constexpr int FT   = F / 32;       // hf32 real f-tiles
  __shared__ float    xs[16][DIN];
  __shared__ float    hs[16][F];
  __shared__ ushort_t gls[16][F];
  __shared__ float    sqs[16];
  __shared__ float    degs[16];
  const int t  = threadIdx.x;
  const int m  = blockIdx.x;
  const int r0 = m * 16;
  const int w = t >> 6, lane = t & 63, g = lane >> 4, q = lane & 15;

  if (RED) {
    constexpr size_t STR = (size_t)NROWS * 160;
    if (t < 16) {
      float d = 0.f;
#pragma unroll
      for (int js = 0; js < 8; ++js)
        d += x[js * STR + (size_t)(r0 + t) * 160 + 128];
      degs[t] = d;
    }
    __syncthreads();
    for (int i = t; i < 16 * DIN; i += 256) {
      int r = i / DIN, c = i % DIN;
      float s = 0.f;
#pragma unroll
      for (int js = 0; js < 8; ++js)
        s += x[js * STR + (size_t)(r0 + r) * 160 + c];
      xs[r][c] = fmaxf(s, 0.f) / degs[r];
    }
  } else {
    for (int i = t; i < 16 * DIN; i += 256)
      xs[i / DIN][i % DIN] = x[(size_t)(r0 + i / DIN) * DIN + (i % DIN)];
  }
  if (t < 16) sqs[t] = 0.f;
  __syncthreads();

  bf16x8 aF[KKD];
#pragma unroll
  for (int kk = 0; kk < KKD; ++kk) {
    const float* src = &xs[q][32 * kk + 8 * g];
    __align__(16) ushort_t tmp[8];
#pragma unroll
    for (int e = 0; e < 8; ++e) tmp[e] = f2bf(src[e]);
    aF[kk] = *(const bf16x8*)tmp;
  }
  f32x4 acc[NCTW];
#pragma unroll
  for (int tl = 0; tl < NCTW; ++tl) {
    int c = 16 * (NCTW * w + tl) + q;
    float bv = (c < F) ? b1[c] : b2[c - F];
    acc[tl] = (f32x4){bv, bv, bv, bv};
  }
#pragma unroll
  for (int kk = 0; kk < KKD; ++kk)
#pragma unroll
    for (int tl = 0; tl < NCTW; ++tl) {
      bf16x8 bW = *(const bf16x8*)(Wf +
          ((size_t)(kk * NCT) + (NCTW * w + tl)) * 512 + lane * 8);
      acc[tl] = __builtin_amdgcn_mfma_f32_16x16x32_bf16(aF[kk], bW, acc[tl], 0, 0, 0);
    }
#pragma unroll
  for (int tl = 0; tl < NCTW; ++tl)
#pragma unroll
    for (int r = 0; r < 4; ++r) {
      int row = 4 * g + r, c = 16 * (NCTW * w + tl) + q;
      float v = acc[tl][r];
      if (c < F) {
        float gv = fmaxf(v, 0.f);
        ushort_t gb = f2bf(gv);
        gls[row][c] = gb;
        float gf = bf2f(gb);
        atomicAdd(&sqs[row], gf * gf);
      } else {
        hs[row][c - F] = v;
      }
    }
  __syncthreads();
  if (t < 16) sq[r0 + t] = sqs[t];

  // ---- glf32 writer: block rows are half a 32-row tile (halves by m&1)
  if (t < 32 * (F / 16)) {
    int ch = t >> 5, li = t & 31;
    int lane2 = 32 * (li >> 4) + 16 * (m & 1) + (li & 15);
    const uint4* src = (const uint4*)&gls[li & 15][16 * ch + 8 * (li >> 4)];
    *(uint4*)(glf32 + ((size_t)(m >> 1) * (F / 16) + ch) * 512 + lane2 * 8) = *src;
  }
  // ---- hf32 writer: block = one 16-j window (jw = m)
  if (t < FT * 64) {
    int ft = t >> 6, l2 = t & 63;
    __align__(16) ushort_t tmp[8];
#pragma unroll
    for (int e = 0; e < 8; ++e)
      tmp[e] = f2bf(hs[8 * (l2 >> 5) + e][32 * ft + (l2 & 31)]);
    *(uint4*)(hf32 + ((size_t)m * FT + ft) * 512 + l2 * 8) = *(const uint4*)tmp;
  }
}

// ---------------------------------------------------------------------------
// fused (R21 = R20 generalized to NW 32-j windows per iteration):
// per iter stage NW*32 j's (contiguous regions + NW/2 64-lane sq loads),
// run NW independent S^T MFMA chains, then per-window sigmoid -> cvt_pk +
// permlane32_swap pack -> PV over 2 K=16 sub-windows. F=128: NW=2 (R20
// schedule, proven). F=64: NW=4 (8 iterations -- the f64 loop was the most
// latency-dominated; quadruple independent work per barrier quantum).
// ---------------------------------------------------------------------------
template<int F, int NW>
__global__ __launch_bounds__(256) void fused_kernel(
    const ushort_t* __restrict__ glf32, const float* __restrict__ sq,
    const ushort_t* __restrict__ hf32,
    const float* __restrict__ temp_p, const float* __restrict__ theta_p,
    float* __restrict__ partial)
{
  constexpr int FT   = F / 32;        // real f-tiles (4 / 2)
  constexpr int FpO  = 32 * (FT + 1); // partial stride (160 / 96)
  constexpr int KKW  = F / 16;        // phase-A K-fragments per window (8/4)
  constexpr int JS   = 8;
  constexpr int JCH  = NROWS / JS;
  constexpr int NIT  = JCH / (32 * NW);   // 16 / 8 iterations
  constexpr int NCHT = NW * KKW + 2 * NW * FT;  // staged chunks (32 both)
  constexpr float EPS = 1.1920929e-07f;
  constexpr float LOG2E = 1.4426950408889634f;
  __shared__ __align__(16) ushort_t stage[NCHT * 512 + 256];  // ~33.5KB

  const int w = threadIdx.x >> 6, lane = threadIdx.x & 63;
  const int hi = lane >> 5, col = lane & 31;
  const int n  = blockIdx.x + (int)gridDim.x * blockIdx.y;
  const int bx = n >> 3, by = n & 7;        // XCD-bijective (512 = 8*64)
  const int irow  = bx * 128 + 32 * w;      // wave's 32 i-rows
  const int jbase = by * JCH;
  const float c1 = 1.0f + *temp_p;
  const float c0 = 5.0f + *theta_p;
  const float k1 = c1 * LOG2E;
  const float k0 = -c0 * LOG2E;

  // hoist i-side fragments (B operand) + per-lane sqi
  bf16x8 iF[KKW];
#pragma unroll
  for (int kk = 0; kk < KKW; ++kk)
    iF[kk] = *(const bf16x8*)(glf32 +
        ((size_t)(irow >> 5) * KKW + kk) * 512 + lane * 8);
  const float sqi = sq[irow + col] + EPS;

  // ones f-tile (deg col = first col of tile FT)
  bf16x8 onesF;
  {
    __align__(16) ushort_t tmp[8];
    ushort_t v = (col == 0) ? (ushort_t)0x3F80 : (ushort_t)0;
#pragma unroll
    for (int e = 0; e < 8; ++e) tmp[e] = v;
    onesF = *(const bf16x8*)tmp;
  }

  f32x16 acc[FT + 1];
#pragma unroll
  for (int ft = 0; ft <= FT; ++ft)
#pragma unroll
    for (int r = 0; r < 16; ++r) acc[ft][r] = 0.f;

  const float* sqslot = (const float*)(stage + NCHT * 512);

#pragma unroll 1
  for (int k = 0; k < NIT; ++k) {
    const int j0 = jbase + k * 32 * NW;
    __syncthreads();   // WAR: all waves done reading stage
    {
      // contiguous regions: NW*KKW j-frag chunks, 2*NW*FT h chunks
      const ushort_t* glB = glf32 + (size_t)(j0 >> 5) * KKW * 512;
      const ushort_t* glH = hf32  + (size_t)(j0 >> 4) * FT * 512;
#pragma unroll
      for (int ch = w; ch < NCHT; ch += 4) {
        const ushort_t* src = (ch < NW * KKW)
            ? (glB + (size_t)ch * 512)
            : (glH + (size_t)(ch - NW * KKW) * 512);
        load_lds16(src + lane * 8, stage + ch * 512);
      }
      // sq: NW/2 x 64-lane loads, handled by the top waves
      if (w >= 4 - NW / 2) {
        int slot = w - (4 - NW / 2);
        load_lds4(sq + j0 + 64 * slot + lane, (float*)sqslot + 64 * slot + lane);
      }
    }
    __syncthreads();   // drains vmcnt + barrier

    // ---- phase A: NW independent S^T chains
    f32x16 sacc[NW];
#pragma unroll
    for (int W = 0; W < NW; ++W)
#pragma unroll
      for (int r = 0; r < 16; ++r) sacc[W][r] = 0.f;
#pragma unroll
    for (int kk = 0; kk < KKW; ++kk) {
#pragma unroll
      for (int W = 0; W < NW; ++W) {
        bf16x8 jf = *(const bf16x8*)(stage + (W * KKW + kk) * 512 + lane * 8);
        sacc[W] = __builtin_amdgcn_mfma_f32_32x32x16_bf16(jf, iF[kk], sacc[W], 0, 0, 0);
      }
    }
    // ---- per-window: sigmoid -> pack -> PV (two K=16 sub-windows each)
#pragma unroll
    for (int W = 0; W < NW; ++W) {
      const float* sqlane = sqslot + 32 * W + 4 * hi;
      f32x4 sqjv[4];
#pragma unroll
      for (int G = 0; G < 4; ++G) sqjv[G] = *(const f32x4*)(sqlane + 8 * G);
      float adjv[16];
#pragma unroll
      for (int r = 0; r < 16; ++r) {
        float t1 = sqi + sqjv[r >> 2][r & 3];
        float d  = fmaxf(fmaf(-2.f, sacc[W][r], t1), EPS);
        float e  = __builtin_amdgcn_exp2f(fmaf(k1, __builtin_amdgcn_sqrtf(d), k0));
        adjv[r] = __builtin_amdgcn_rcpf(1.f + e);
      }
      uint_t P0 = cvtpk(adjv[0],  adjv[1]),  P1 = cvtpk(adjv[2],  adjv[3]);
      uint_t P2 = cvtpk(adjv[4],  adjv[5]),  P3 = cvtpk(adjv[6],  adjv[7]);
      uint_t P4 = cvtpk(adjv[8],  adjv[9]),  P5 = cvtpk(adjv[10], adjv[11]);
      uint_t P6 = cvtpk(adjv[12], adjv[13]), P7 = cvtpk(adjv[14], adjv[15]);
      u32x2 sA0 = __builtin_amdgcn_permlane32_swap(P2, P0, false, false);
      u32x2 sA1 = __builtin_amdgcn_permlane32_swap(P3, P1, false, false);
      u32x2 sB0 = __builtin_amdgcn_permlane32_swap(P6, P4, false, false);
      u32x2 sB1 = __builtin_amdgcn_permlane32_swap(P7, P5, false, false);
      u32x4 dw1 = {sA0[1], sA1[1], sA0[0], sA1[0]};   // j-sub 0..15
      u32x4 dw2 = {sB0[1], sB1[1], sB0[0], sB1[0]};   // j-sub 16..31
      bf16x8 PA1 = __builtin_bit_cast(bf16x8, dw1);
      bf16x8 PA2 = __builtin_bit_cast(bf16x8, dw2);
#pragma unroll
      for (int o2 = 0; o2 < 2; ++o2) {
        int o = 2 * W + o2;               // global K=16 sub-window
        bf16x8 PA = o2 ? PA2 : PA1;
#pragma unroll
        for (int ft = 0; ft <= FT; ++ft) {
          bf16x8 hfr = (ft == FT)
              ? onesF
              : *(const bf16x8*)(stage + (NW * KKW + o * FT + ft) * 512 + lane * 8);
          acc[ft] = __builtin_amdgcn_mfma_f32_32x32x16_bf16(PA, hfr, acc[ft], 0, 0, 0);
        }
      }
    }
  }

  // ---- epilogue: D rows = i = (r&3)+8(r>>2)+4hi; cols = 32ft+col
  float* op = partial + ((size_t)by * NROWS + irow) * FpO + col;
#pragma unroll
  for (int ft = 0; ft <= FT; ++ft)
#pragma unroll
    for (int r = 0; r < 16; ++r) {
      int row = (r & 3) + 8 * (r >> 2) + 4 * hi;
      op[(size_t)row * FpO + 32 * ft] = acc[ft][r];
    }
}

// out = softmax(sum_js(partial)/deg); partial stride 96, deg col 64
__global__ __launch_bounds__(256) void reduce_softmax_kernel(
    const float* __restrict__ partial, float* __restrict__ out)
{
  int t = threadIdx.x;
  int r = blockIdx.x * 4 + (t >> 6), c = t & 63;
  size_t base = (size_t)r * 96;
  size_t stride = (size_t)NROWS * 96;
  float v = 0.f, d = 0.f;
#pragma unroll
  for (int js = 0; js < 8; ++js) {
    v += partial[js * stride + base + c];
    d += partial[js * stride + base + 64];
  }
  v /= d;
  float m = v;
  for (int o = 32; o > 0; o >>= 1) m = fmaxf(m, __shfl_xor(m, o, 64));
  float e = __expf(v - m);
  float s = e;
  for (int o = 32; o > 0; o >>= 1) s += __shfl_xor(s, o, 64);
  out[(size_t)r * 64 + c] = e / s;
}

extern "C" void kernel_launch(void* const* d_in, const int* in_sizes, int n_in,
                              void* d_out, int out_size, void* d_ws, size_t ws_size,
                              hipStream_t stream) {
  const float* feat  = (const float*)d_in[0];
  const float* Wgl0  = (const float*)d_in[6];
  const float* bgl0  = (const float*)d_in[7];
  const float* Wgnn0 = (const float*)d_in[8];
  const float* bgnn0 = (const float*)d_in[9];
  const float* Wgl1  = (const float*)d_in[10];
  const float* bgl1  = (const float*)d_in[11];
  const float* Wgnn1 = (const float*)d_in[12];
  const float* bgnn1 = (const float*)d_in[13];
  const float* temp  = (const float*)d_in[14];
  const float* theta = (const float*)d_in[15];
  float* out = (float*)d_out;

  char* ws = (char*)d_ws;
  size_t off = 0;
  auto alloc = [&](size_t bytes) {
    char* p = ws + off;
    off = (off + bytes + 255) & ~(size_t)255;
    return p;
  };
  float*    par0 = (float*)alloc(8ull * NROWS * 160 * 4);  // 41.9 MB
  float*    par1 = par0;  // aliased: par0 fully consumed by lin1 first
  ushort_t* glf0 = (ushort_t*)alloc((8192ull / 32) * 8 * 512 * 2);  // 2 MB
  ushort_t* glf1 = (ushort_t*)alloc((8192ull / 32) * 4 * 512 * 2);  // 1 MB
  ushort_t* hf0  = (ushort_t*)alloc((8192ull / 16) * 4 * 512 * 2);  // 2 MB
  ushort_t* hf1  = (ushort_t*)alloc((8192ull / 16) * 2 * 512 * 2);  // 1 MB
  float*    sq0  = (float*)alloc(8192ull * 4);
  float*    sq1  = (float*)alloc(8192ull * 4);
  ushort_t* Wf0  = (ushort_t*)alloc(8ull * 16 * 512 * 2);   // 128 KB
  ushort_t* Wf1  = (ushort_t*)alloc(4ull * 8 * 512 * 2);    // 32 KB

  prep_w_kernel<256, 128><<<256, 256, 0, stream>>>(Wgl0, Wgnn0, Wf0);
  prep_w_kernel<128, 64><<<64, 256, 0, stream>>>(Wgl1, Wgnn1, Wf1);

  lin_kernel<256, 128, false><<<512, 256, 0, stream>>>(feat, Wf0, bgl0, bgnn0, glf0, sq0, hf0);
  fused_kernel<128, 2><<<dim3(64, 8), 256, 0, stream>>>(glf0, sq0, hf0, temp, theta, par0);

  lin_kernel<128, 64, true><<<512, 256, 0, stream>>>(par0, Wf1, bgl1, bgnn1, glf1, sq1, hf1);
  fused_kernel<64, 4><<<dim3(64, 8), 256, 0, stream>>>(glf1, sq1, hf1, temp, theta, par1);
  reduce_softmax_kernel<<<2048, 256, 0, stream>>>(par1, out);
}

// Round 22
// 131.694 us; speedup vs baseline: 1.1337x; 1.0410x over previous
//
#include <hip/hip_runtime.h>
#include <hip/hip_bf16.h>

#define NROWS 8192

typedef __bf16 bf16x8 __attribute__((ext_vector_type(8)));
typedef float f32x4 __attribute__((ext_vector_type(4)));
typedef float f32x16 __attribute__((ext_vector_type(16)));
typedef unsigned int u32x2 __attribute__((ext_vector_type(2)));
typedef unsigned int u32x4 __attribute__((ext_vector_type(4)));
typedef unsigned short ushort_t;
typedef unsigned int uint_t;

__device__ __forceinline__ ushort_t f2bf(float f) {
  uint_t u = __builtin_bit_cast(uint_t, f);
  u += 0x7fffu + ((u >> 16) & 1u);   // round-to-nearest-even
  return (ushort_t)(u >> 16);
}
__device__ __forceinline__ float bf2f(ushort_t h) {
  uint_t u = ((uint_t)h) << 16;
  return __builtin_bit_cast(float, u);
}
// pack two f32 -> dword of 2 bf16 (lo = first arg)
__device__ __forceinline__ uint_t cvtpk(float lo, float hi) {
  uint_t r;
  asm("v_cvt_pk_bf16_f32 %0, %1, %2" : "=v"(r) : "v"(lo), "v"(hi));
  return r;
}
// async global->LDS DMA; LDS dest = uniform base + lane*size
__device__ __forceinline__ void load_lds16(const ushort_t* g, ushort_t* l) {
  __builtin_amdgcn_global_load_lds(
      (const __attribute__((address_space(1))) unsigned int*)g,
      (__attribute__((address_space(3))) unsigned int*)l, 16, 0, 0);
}
__device__ __forceinline__ void load_lds4(const float* g, float* l) {
  __builtin_amdgcn_global_load_lds(
      (const __attribute__((address_space(1))) unsigned int*)g,
      (__attribute__((address_space(3))) unsigned int*)l, 4, 0, 0);
}

// ---------------------------------------------------------------------------
// prep_w_both (R22): pack BOTH layers' [W1|W2] into fragment-major bf16 in
// one dispatch. Blocks [0,256) -> layer 0 (DIN=256,F=128); [256,320) ->
// layer 1 (DIN=128,F=64).
// ---------------------------------------------------------------------------
__global__ __launch_bounds__(256) void prep_w_both(
    const float* __restrict__ W1a, const float* __restrict__ W2a,
    ushort_t* __restrict__ Wfa,
    const float* __restrict__ W1b, const float* __restrict__ W2b,
    ushort_t* __restrict__ Wfb)
{
  int b = blockIdx.x;
  if (b < 256) {
    constexpr int NCT = 16;  // F=128
    int idx = b * 256 + threadIdx.x;
    int e = idx & 7, lane = (idx >> 3) & 63;
    int ct = (idx >> 9) % NCT, kk = (idx >> 9) / NCT;
    int g = lane >> 4, q = lane & 15;
    int k = 32 * kk + 8 * g + e, c = 16 * ct + q;
    float v = (c < 128) ? W1a[(size_t)k * 128 + c]
                        : W2a[(size_t)k * 128 + (c - 128)];
    Wfa[idx] = f2bf(v);
  } else {
    constexpr int NCT = 8;   // F=64
    int idx = (b - 256) * 256 + threadIdx.x;
    int e = idx & 7, lane = (idx >> 3) & 63;
    int ct = (idx >> 9) % NCT, kk = (idx >> 9) / NCT;
    int g = lane >> 4, q = lane & 15;
    int k = 32 * kk + 8 * g + e, c = 16 * ct + q;
    float v = (c < 64) ? W1b[(size_t)k * 64 + c]
                       : W2b[(size_t)k * 64 + (c - 64)];
    Wfb[idx] = f2bf(v);
  }
}

// ---------------------------------------------------------------------------
// lin (R22 = R19): MFMA GEMM for [gl|h] = x @ [W1|W2] + b. RED=true: x
// produced inline from the 8 partial slabs (stride 160, fp32). Writers emit
// 32x32-fragment-major glf32 / hf32 and sq.
// ---------------------------------------------------------------------------
template<int DIN, int F, bool RED>
__global__ __launch_bounds__(256) void lin_kernel(
    const float* __restrict__ x, const ushort_t* __restrict__ Wf,
    const float* __restrict__ b1, const float* __restrict__ b2,
    ushort_t* __restrict__ glf32, float* __restrict__ sq, ushort_t* __restrict__ hf32)
{
  constexpr int KKD  = DIN / 32;     // GEMM K-fragments
  constexpr int NCT  = (2 * F) / 16; // output col-tiles (gl|h)
  constexpr int NCTW = NCT / 4;      // col-tiles per wave
  constexpr int FT   = F / 32;       // hf32 real f-tiles
  __shared__ float    xs[16][DIN];
  __shared__ float    hs[16][F];
  __shared__ ushort_t gls[16][F];
  __shared__ float    sqs[16];
  __shared__ float    degs[16];
  const int t  = threadIdx.x;
  const int m  = blockIdx.x;
  const int r0 = m * 16;
  const int w = t >> 6, lane = t & 63, g = lane >> 4, q = lane & 15;

  if (RED) {
    constexpr size_t STR = (size_t)NROWS * 160;
    if (t < 16) {
      float d = 0.f;
#pragma unroll
      for (int js = 0; js < 8; ++js)
        d += x[js * STR + (size_t)(r0 + t) * 160 + 128];
      degs[t] = d;
    }
    __syncthreads();
    for (int i = t; i < 16 * DIN; i += 256) {
      int r = i / DIN, c = i % DIN;
      float s = 0.f;
#pragma unroll
      for (int js = 0; js < 8; ++js)
        s += x[js * STR + (size_t)(r0 + r) * 160 + c];
      xs[r][c] = fmaxf(s, 0.f) / degs[r];
    }
  } else {
    for (int i = t; i < 16 * DIN; i += 256)
      xs[i / DIN][i % DIN] = x[(size_t)(r0 + i / DIN) * DIN + (i % DIN)];
  }
  if (t < 16) sqs[t] = 0.f;
  __syncthreads();

  bf16x8 aF[KKD];
#pragma unroll
  for (int kk = 0; kk < KKD; ++kk) {
    const float* src = &xs[q][32 * kk + 8 * g];
    __align__(16) ushort_t tmp[8];
#pragma unroll
    for (int e = 0; e < 8; ++e) tmp[e] = f2bf(src[e]);
    aF[kk] = *(const bf16x8*)tmp;
  }
  f32x4 acc[NCTW];
#pragma unroll
  for (int tl = 0; tl < NCTW; ++tl) {
    int c = 16 * (NCTW * w + tl) + q;
    float bv = (c < F) ? b1[c] : b2[c - F];
    acc[tl] = (f32x4){bv, bv, bv, bv};
  }
#pragma unroll
  for (int kk = 0; kk < KKD; ++kk)
#pragma unroll
    for (int tl = 0; tl < NCTW; ++tl) {
      bf16x8 bW = *(const bf16x8*)(Wf +
          ((size_t)(kk * NCT) + (NCTW * w + tl)) * 512 + lane * 8);
      acc[tl] = __builtin_amdgcn_mfma_f32_16x16x32_bf16(aF[kk], bW, acc[tl], 0, 0, 0);
    }
#pragma unroll
  for (int tl = 0; tl < NCTW; ++tl)
#pragma unroll
    for (int r = 0; r < 4; ++r) {
      int row = 4 * g + r, c = 16 * (NCTW * w + tl) + q;
      float v = acc[tl][r];
      if (c < F) {
        float gv = fmaxf(v, 0.f);
        ushort_t gb = f2bf(gv);
        gls[row][c] = gb;
        float gf = bf2f(gb);
        atomicAdd(&sqs[row], gf * gf);
      } else {
        hs[row][c - F] = v;
      }
    }
  __syncthreads();
  if (t < 16) sq[r0 + t] = sqs[t];

  // ---- glf32 writer: block rows are half a 32-row tile (halves by m&1)
  if (t < 32 * (F / 16)) {
    int ch = t >> 5, li = t & 31;
    int lane2 = 32 * (li >> 4) + 16 * (m & 1) + (li & 15);
    const uint4* src = (const uint4*)&gls[li & 15][16 * ch + 8 * (li >> 4)];
    *(uint4*)(glf32 + ((size_t)(m >> 1) * (F / 16) + ch) * 512 + lane2 * 8) = *src;
  }
  // ---- hf32 writer: block = one 16-j window (jw = m)
  if (t < FT * 64) {
    int ft = t >> 6, l2 = t & 63;
    __align__(16) ushort_t tmp[8];
#pragma unroll
    for (int e = 0; e < 8; ++e)
      tmp[e] = f2bf(hs[8 * (l2 >> 5) + e][32 * ft + (l2 & 31)]);
    *(uint4*)(hf32 + ((size_t)m * FT + ft) * 512 + l2 * 8) = *(const uint4*)tmp;
  }
}

// ---------------------------------------------------------------------------
// fused (R22 = R21 + BF16OUT epilogue flag): NW 32-j windows per iteration,
// NW independent S^T chains -> in-register sigmoid -> cvt_pk+permlane pack
// -> PV. BF16OUT=true (layer 1): partials stored as bf16 (consumed only by
// softmax; error ~2e-6 on output) -- halves write+read traffic.
// ---------------------------------------------------------------------------
template<int F, int NW, bool BF16OUT>
__global__ __launch_bounds__(256) void fused_kernel(
    const ushort_t* __restrict__ glf32, const float* __restrict__ sq,
    const ushort_t* __restrict__ hf32,
    const float* __restrict__ temp_p, const float* __restrict__ theta_p,
    float* __restrict__ partial)
{
  constexpr int FT   = F / 32;        // real f-tiles (4 / 2)
  constexpr int FpO  = 32 * (FT + 1); // partial stride (160 / 96)
  constexpr int KKW  = F / 16;        // phase-A K-fragments per window (8/4)
  constexpr int JS   = 8;
  constexpr int JCH  = NROWS / JS;
  constexpr int NIT  = JCH / (32 * NW);   // 16 / 8 iterations
  constexpr int NCHT = NW * KKW + 2 * NW * FT;  // staged chunks (32 both)
  constexpr float EPS = 1.1920929e-07f;
  constexpr float LOG2E = 1.4426950408889634f;
  __shared__ __align__(16) ushort_t stage[NCHT * 512 + 256];  // ~33.5KB

  const int w = threadIdx.x >> 6, lane = threadIdx.x & 63;
  const int hi = lane >> 5, col = lane & 31;
  const int n  = blockIdx.x + (int)gridDim.x * blockIdx.y;
  const int bx = n >> 3, by = n & 7;        // XCD-bijective (512 = 8*64)
  const int irow  = bx * 128 + 32 * w;      // wave's 32 i-rows
  const int jbase = by * JCH;
  const float c1 = 1.0f + *temp_p;
  const float c0 = 5.0f + *theta_p;
  const float k1 = c1 * LOG2E;
  const float k0 = -c0 * LOG2E;

  // hoist i-side fragments (B operand) + per-lane sqi
  bf16x8 iF[KKW];
#pragma unroll
  for (int kk = 0; kk < KKW; ++kk)
    iF[kk] = *(const bf16x8*)(glf32 +
        ((size_t)(irow >> 5) * KKW + kk) * 512 + lane * 8);
  const float sqi = sq[irow + col] + EPS;

  // ones f-tile (deg col = first col of tile FT)
  bf16x8 onesF;
  {
    __align__(16) ushort_t tmp[8];
    ushort_t v = (col == 0) ? (ushort_t)0x3F80 : (ushort_t)0;
#pragma unroll
    for (int e = 0; e < 8; ++e) tmp[e] = v;
    onesF = *(const bf16x8*)tmp;
  }

  f32x16 acc[FT + 1];
#pragma unroll
  for (int ft = 0; ft <= FT; ++ft)
#pragma unroll
    for (int r = 0; r < 16; ++r) acc[ft][r] = 0.f;

  const float* sqslot = (const float*)(stage + NCHT * 512);

#pragma unroll 1
  for (int k = 0; k < NIT; ++k) {
    const int j0 = jbase + k * 32 * NW;
    __syncthreads();   // WAR: all waves done reading stage
    {
      // contiguous regions: NW*KKW j-frag chunks, 2*NW*FT h chunks
      const ushort_t* glB = glf32 + (size_t)(j0 >> 5) * KKW * 512;
      const ushort_t* glH = hf32  + (size_t)(j0 >> 4) * FT * 512;
#pragma unroll
      for (int ch = w; ch < NCHT; ch += 4) {
        const ushort_t* src = (ch < NW * KKW)
            ? (glB + (size_t)ch * 512)
            : (glH + (size_t)(ch - NW * KKW) * 512);
        load_lds16(src + lane * 8, stage + ch * 512);
      }
      // sq: NW/2 x 64-lane loads, handled by the top waves
      if (w >= 4 - NW / 2) {
        int slot = w - (4 - NW / 2);
        load_lds4(sq + j0 + 64 * slot + lane, (float*)sqslot + 64 * slot + lane);
      }
    }
    __syncthreads();   // drains vmcnt + barrier

    // ---- phase A: NW independent S^T chains
    f32x16 sacc[NW];
#pragma unroll
    for (int W = 0; W < NW; ++W)
#pragma unroll
      for (int r = 0; r < 16; ++r) sacc[W][r] = 0.f;
#pragma unroll
    for (int kk = 0; kk < KKW; ++kk) {
#pragma unroll
      for (int W = 0; W < NW; ++W) {
        bf16x8 jf = *(const bf16x8*)(stage + (W * KKW + kk) * 512 + lane * 8);
        sacc[W] = __builtin_amdgcn_mfma_f32_32x32x16_bf16(jf, iF[kk], sacc[W], 0, 0, 0);
      }
    }
    // ---- per-window: sigmoid -> pack -> PV (two K=16 sub-windows each)
#pragma unroll
    for (int W = 0; W < NW; ++W) {
      const float* sqlane = sqslot + 32 * W + 4 * hi;
      f32x4 sqjv[4];
#pragma unroll
      for (int G = 0; G < 4; ++G) sqjv[G] = *(const f32x4*)(sqlane + 8 * G);
      float adjv[16];
#pragma unroll
      for (int r = 0; r < 16; ++r) {
        float t1 = sqi + sqjv[r >> 2][r & 3];
        float d  = fmaxf(fmaf(-2.f, sacc[W][r], t1), EPS);
        float e  = __builtin_amdgcn_exp2f(fmaf(k1, __builtin_amdgcn_sqrtf(d), k0));
        adjv[r] = __builtin_amdgcn_rcpf(1.f + e);
      }
      uint_t P0 = cvtpk(adjv[0],  adjv[1]),  P1 = cvtpk(adjv[2],  adjv[3]);
      uint_t P2 = cvtpk(adjv[4],  adjv[5]),  P3 = cvtpk(adjv[6],  adjv[7]);
      uint_t P4 = cvtpk(adjv[8],  adjv[9]),  P5 = cvtpk(adjv[10], adjv[11]);
      uint_t P6 = cvtpk(adjv[12], adjv[13]), P7 = cvtpk(adjv[14], adjv[15]);
      u32x2 sA0 = __builtin_amdgcn_permlane32_swap(P2, P0, false, false);
      u32x2 sA1 = __builtin_amdgcn_permlane32_swap(P3, P1, false, false);
      u32x2 sB0 = __builtin_amdgcn_permlane32_swap(P6, P4, false, false);
      u32x2 sB1 = __builtin_amdgcn_permlane32_swap(P7, P5, false, false);
      u32x4 dw1 = {sA0[1], sA1[1], sA0[0], sA1[0]};   // j-sub 0..15
      u32x4 dw2 = {sB0[1], sB1[1], sB0[0], sB1[0]};   // j-sub 16..31
      bf16x8 PA1 = __builtin_bit_cast(bf16x8, dw1);
      bf16x8 PA2 = __builtin_bit_cast(bf16x8, dw2);
#pragma unroll
      for (int o2 = 0; o2 < 2; ++o2) {
        int o = 2 * W + o2;               // global K=16 sub-window
        bf16x8 PA = o2 ? PA2 : PA1;
#pragma unroll
        for (int ft = 0; ft <= FT; ++ft) {
          bf16x8 hfr = (ft == FT)
              ? onesF
              : *(const bf16x8*)(stage + (NW * KKW + o * FT + ft) * 512 + lane * 8);
          acc[ft] = __builtin_amdgcn_mfma_f32_32x32x16_bf16(PA, hfr, acc[ft], 0, 0, 0);
        }
      }
    }
  }

  // ---- epilogue: D rows = i = (r&3)+8(r>>2)+4hi; cols = 32ft+col
  if (BF16OUT) {
    ushort_t* op = (ushort_t*)partial + ((size_t)by * NROWS + irow) * FpO + col;
#pragma unroll
    for (int ft = 0; ft <= FT; ++ft)
#pragma unroll
      for (int r = 0; r < 16; ++r) {
        int row = (r & 3) + 8 * (r >> 2) + 4 * hi;
        op[(size_t)row * FpO + 32 * ft] = f2bf(acc[ft][r]);
      }
  } else {
    float* op = partial + ((size_t)by * NROWS + irow) * FpO + col;
#pragma unroll
    for (int ft = 0; ft <= FT; ++ft)
#pragma unroll
      for (int r = 0; r < 16; ++r) {
        int row = (r & 3) + 8 * (r >> 2) + 4 * hi;
        op[(size_t)row * FpO + 32 * ft] = acc[ft][r];
      }
  }
}

// out = softmax(sum_js(partial)/deg); bf16 partials, stride 96, deg col 64
__global__ __launch_bounds__(256) void reduce_softmax_kernel(
    const ushort_t* __restrict__ partial, float* __restrict__ out)
{
  int t = threadIdx.x;
  int r = blockIdx.x * 4 + (t >> 6), c = t & 63;
  size_t base = (size_t)r * 96;
  size_t stride = (size_t)NROWS * 96;
  float v = 0.f, d = 0.f;
#pragma unroll
  for (int js = 0; js < 8; ++js) {
    v += bf2f(partial[js * stride + base + c]);
    d += bf2f(partial[js * stride + base + 64]);
  }
  v /= d;
  float m = v;
  for (int o = 32; o > 0; o >>= 1) m = fmaxf(m, __shfl_xor(m, o, 64));
  float e = __expf(v - m);
  float s = e;
  for (int o = 32; o > 0; o >>= 1) s += __shfl_xor(s, o, 64);
  out[(size_t)r * 64 + c] = e / s;
}

extern "C" void kernel_launch(void* const* d_in, const int* in_sizes, int n_in,
                              void* d_out, int out_size, void* d_ws, size_t ws_size,
                              hipStream_t stream) {
  const float* feat  = (const float*)d_in[0];
  const float* Wgl0  = (const float*)d_in[6];
  const float* bgl0  = (const float*)d_in[7];
  const float* Wgnn0 = (const float*)d_in[8];
  const float* bgnn0 = (const float*)d_in[9];
  const float* Wgl1  = (const float*)d_in[10];
  const float* bgl1  = (const float*)d_in[11];
  const float* Wgnn1 = (const float*)d_in[12];
  const float* bgnn1 = (const float*)d_in[13];
  const float* temp  = (const float*)d_in[14];
  const float* theta = (const float*)d_in[15];
  float* out = (float*)d_out;

  char* ws = (char*)d_ws;
  size_t off = 0;
  auto alloc = [&](size_t bytes) {
    char* p = ws + off;
    off = (off + bytes + 255) & ~(size_t)255;
    return p;
  };
  float*    par0 = (float*)alloc(8ull * NROWS * 160 * 4);  // 41.9 MB (fp32)
  float*    par1 = par0;  // aliased; layer-1 partials are bf16 in-place
  ushort_t* glf0 = (ushort_t*)alloc((8192ull / 32) * 8 * 512 * 2);  // 2 MB
  ushort_t* glf1 = (ushort_t*)alloc((8192ull / 32) * 4 * 512 * 2);  // 1 MB
  ushort_t* hf0  = (ushort_t*)alloc((8192ull / 16) * 4 * 512 * 2);  // 2 MB
  ushort_t* hf1  = (ushort_t*)alloc((8192ull / 16) * 2 * 512 * 2);  // 1 MB
  float*    sq0  = (float*)alloc(8192ull * 4);
  float*    sq1  = (float*)alloc(8192ull * 4);
  ushort_t* Wf0  = (ushort_t*)alloc(8ull * 16 * 512 * 2);   // 128 KB
  ushort_t* Wf1  = (ushort_t*)alloc(4ull * 8 * 512 * 2);    // 32 KB

  prep_w_both<<<320, 256, 0, stream>>>(Wgl0, Wgnn0, Wf0, Wgl1, Wgnn1, Wf1);

  lin_kernel<256, 128, false><<<512, 256, 0, stream>>>(feat, Wf0, bgl0, bgnn0, glf0, sq0, hf0);
  fused_kernel<128, 2, false><<<dim3(64, 8), 256, 0, stream>>>(glf0, sq0, hf0, temp, theta, par0);

  lin_kernel<128, 64, true><<<512, 256, 0, stream>>>(par0, Wf1, bgl1, bgnn1, glf1, sq1, hf1);
  fused_kernel<64, 4, true><<<dim3(64, 8), 256, 0, stream>>>(glf1, sq1, hf1, temp, theta, par1);
  reduce_softmax_kernel<<<2048, 256, 0, stream>>>((const ushort_t*)par1, out);
}